// Round 10
// baseline (147.716 us; speedup 1.0000x reference)
//
#include <hip/hip_runtime.h>
#include <hip/hip_fp16.h>
#include <math.h>

// ---------------------------------------------------------------------------
// RGAT (2-layer graph attention) on MI355X — round 26.
// N=50000, E=800000 (avg deg 16), IN=64, HID=64, OUT=8.
// Round-26: merge K2+K3 via software device barrier. nbuck=196 blocks of
// 1024 thr (74KB LDS) -> 2 blocks/CU => all 196 co-resident on 256 CUs, so
// an atomic-counter barrier is deadlock-free (unlike r21/r22's 978-block
// cooperative attempt). Layer-2 reuses ALL of layer-1's LDS state across
// the barrier: svl/dlocl/evl records, lbase/degl offsets, eds (ed2 is
// block-local by construction -> never leaves LDS). Deletes: one launch,
// K3's ped re-read (6.4MB), hist+scan+scatter rebuild, record restage.
// Cross-XCD visibility: es2/h2 written with __hip_atomic_store(AGENT),
// read with __hip_atomic_load(AGENT) (per-XCD L2s are not coherent).
// K1 (part_gemm) unchanged. h1 stays fp8 e4m3 (3.2MB, L2-resident).
// ---------------------------------------------------------------------------

#define CHUNK 4096
#define NBKT  256
#define CAP   6144   // per-bucket capacity (uniform random: 32-sigma margin)

typedef unsigned long long ull;
typedef float v2f __attribute__((ext_vector_type(2)));

union F2U { float2 f; ull u; };

struct PartSmem {
    int lhist[NBKT], lbase[NBKT], lcur[NBKT], gbase[NBKT];
    ull buf[CHUNK];
};
struct GemmSmem {
    float4 Wl[64 * 16];
    float  Xt[64 * 64];
};
union FusedSmem { PartSmem p; GemmSmem g; };

// ---------------- fused: edge partition (blocks < nchunks) + layer-1 GEMM ---

__global__ void __launch_bounds__(256) part_gemm_kernel(
    const int* __restrict__ src, const int* __restrict__ dst,
    const float* __restrict__ ev, int* __restrict__ bcnt,
    ull* __restrict__ ped, int E, int nchunks,
    const float* __restrict__ x, const float* __restrict__ W,
    const float* __restrict__ a_src, const float* __restrict__ a_dst,
    unsigned* __restrict__ h, float* __restrict__ es, float* __restrict__ ed,
    int N)
{
    __shared__ FusedSmem sm;
    const int t = threadIdx.x;

    if (blockIdx.x < nchunks) {
        // ---------------- partition path ----------------
        int e0 = blockIdx.x * CHUNK;
        int cnt = min(CHUNK, E - e0);
        sm.p.lhist[t] = 0;
        __syncthreads();
        for (int i = t; i < cnt; i += 256)
            atomicAdd(&sm.p.lhist[dst[e0 + i] >> 8], 1);
        __syncthreads();
        int myc = sm.p.lhist[t];
        sm.p.lbase[t] = myc;
        __syncthreads();
        for (int o = 1; o < 256; o <<= 1) {
            int add = (t >= o) ? sm.p.lbase[t - o] : 0;
            __syncthreads();
            sm.p.lbase[t] += add;
            __syncthreads();
        }
        int excl = sm.p.lbase[t] - myc;
        sm.p.gbase[t] = myc ? atomicAdd(&bcnt[t], myc) : 0;
        __syncthreads();
        sm.p.lbase[t] = excl;
        sm.p.lcur[t] = excl;
        __syncthreads();
        for (int i = t; i < cnt; i += 256) {
            int e = e0 + i;
            int d = dst[e];
            int b = d >> 8;
            unsigned p = (unsigned)src[e] | ((unsigned)(d & 255) << 16)
                       | ((unsigned)b << 24);
            ull q = (ull)p | ((ull)__float_as_uint(ev[e]) << 32);
            int r = atomicAdd(&sm.p.lcur[b], 1);
            sm.p.buf[r] = q;
        }
        __syncthreads();
        for (int i = t; i < cnt; i += 256) {
            ull q = sm.p.buf[i];
            int b = (int)((q >> 24) & 255);
            ped[(size_t)b * CAP + sm.p.gbase[b] + i - sm.p.lbase[b]] = q;
        }
        return;
    }

    // ---------------- GEMM path ----------------
    const int n0 = (blockIdx.x - nchunks) * 64;

    #pragma unroll
    for (int i = 0; i < 4; ++i)
        sm.g.Wl[t + i * 256] = ((const float4*)W)[t + i * 256];

    #pragma unroll
    for (int i = 0; i < 4; ++i) {
        int f   = t + i * 256;
        int row = f >> 4, kq = f & 15;
        int grow = n0 + row;
        float4 v = make_float4(0.f, 0.f, 0.f, 0.f);
        if (grow < N) v = ((const float4*)x)[(size_t)grow * 16 + kq];
        int rs = row ^ ((kq & 3) << 2);
        sm.g.Xt[(kq * 4 + 0) * 64 + rs] = v.x;
        sm.g.Xt[(kq * 4 + 1) * 64 + rs] = v.y;
        sm.g.Xt[(kq * 4 + 2) * 64 + rs] = v.z;
        sm.g.Xt[(kq * 4 + 3) * 64 + rs] = v.w;
    }

    const int tx = t & 15;
    const int ty = t >> 4;
    const float4 asv = ((const float4*)a_src)[tx];
    const float4 adv = ((const float4*)a_dst)[tx];
    __syncthreads();

    float4 acc0 = make_float4(0.f,0.f,0.f,0.f);
    float4 acc1 = make_float4(0.f,0.f,0.f,0.f);
    float4 acc2 = make_float4(0.f,0.f,0.f,0.f);
    float4 acc3 = make_float4(0.f,0.f,0.f,0.f);

    #pragma unroll 8
    for (int k = 0; k < 64; ++k) {
        int swz = (k >> 2) & 3;
        const float4 xr = *(const float4*)&sm.g.Xt[k * 64 + ((ty ^ swz) << 2)];
        const float4 wv = sm.g.Wl[k * 16 + tx];
        acc0.x += xr.x * wv.x; acc0.y += xr.x * wv.y;
        acc0.z += xr.x * wv.z; acc0.w += xr.x * wv.w;
        acc1.x += xr.y * wv.x; acc1.y += xr.y * wv.y;
        acc1.z += xr.y * wv.z; acc1.w += xr.y * wv.w;
        acc2.x += xr.z * wv.x; acc2.y += xr.z * wv.y;
        acc2.z += xr.z * wv.z; acc2.w += xr.z * wv.w;
        acc3.x += xr.w * wv.x; acc3.y += xr.w * wv.y;
        acc3.z += xr.w * wv.z; acc3.w += xr.w * wv.w;
    }

    float4 accs[4] = {acc0, acc1, acc2, acc3};
    #pragma unroll
    for (int r = 0; r < 4; ++r) {
        int grow = n0 + ty * 4 + r;
        float4 a = accs[r];
        if (grow < N) {
            int lo = __builtin_amdgcn_cvt_pk_fp8_f32(a.x, a.y, 0, false);
            int pk = __builtin_amdgcn_cvt_pk_fp8_f32(a.z, a.w, lo, true);
            h[(size_t)grow * 16 + tx] = (unsigned)pk;
        }
        float ps = a.x * asv.x + a.y * asv.y + a.z * asv.z + a.w * asv.w;
        float pd = a.x * adv.x + a.y * adv.y + a.z * adv.z + a.w * adv.w;
        #pragma unroll
        for (int o = 8; o > 0; o >>= 1) {
            ps += __shfl_xor(ps, o);
            pd += __shfl_xor(pd, o);
        }
        if (tx == 0 && grow < N) { es[grow] = ps; ed[grow] = pd; }
    }
}

// ---------------- fused layers 1+2: CSR (LDS) + agg64 + BARRIER + agg8 ------
// One block per bucket (256 nodes), 1024 threads, persistent across both
// layers. LDS state (records, offsets, eds) survives the device barrier.

__global__ void __launch_bounds__(1024) fused_l12_kernel(
    const ull* __restrict__ ped, const int* __restrict__ bcnt,
    const float* __restrict__ es1, const float* __restrict__ ed1,
    const unsigned* __restrict__ h1, const float* __restrict__ b1,
    const float* __restrict__ W2, const float* __restrict__ a2s,
    const float* __restrict__ a2d, float* __restrict__ h2,
    float* __restrict__ es2, const float* __restrict__ b2,
    float* __restrict__ out, int N, int nbuck, int* __restrict__ barrier_ctr)
{
    __shared__ int    lhist[256], lbase[256], lcur[256], degl[256];
    __shared__ float  den[256], eds[256];
    __shared__ float  W2s[64 * 8];
    __shared__ float  wv[CAP];
    __shared__ float  evl[CAP];
    __shared__ unsigned short svl[CAP];
    __shared__ unsigned char  dlocl[CAP];

    const int b = blockIdx.x, t = threadIdx.x;
    const int cnt = min(bcnt[b], CAP);
    const size_t base = (size_t)b * CAP;

    if (t < 256) {
        const int nodeT = b * 256 + t;
        lhist[t] = 0;
        den[t] = 0.f;
        eds[t] = (nodeT < N) ? ed1[nodeT] : 0.f;
    }
    if (t < 128) ((float4*)W2s)[t] = ((const float4*)W2)[t];
    __syncthreads();

    // -------- CSR build in LDS --------
    for (int i = t; i < cnt; i += 1024)
        atomicAdd(&lhist[(int)((ped[base + i] >> 16) & 255)], 1);
    __syncthreads();
    int myc = (t < 256) ? lhist[t] : 0;
    if (t < 256) lbase[t] = myc;
    __syncthreads();
    for (int o = 1; o < 256; o <<= 1) {
        int add = (t >= o && t < 256) ? lbase[t - o] : 0;
        __syncthreads();
        if (t < 256) lbase[t] += add;
        __syncthreads();
    }
    if (t < 256) {
        lcur[t] = lbase[t] - myc;
        degl[t] = myc;
    }
    __syncthreads();
    if (t < 256) lbase[t] -= myc;       // lbase := exclusive offsets
    __syncthreads();

    // scatter + layer-1 weight precompute (one exp per edge)
    for (int i = t; i < cnt; i += 1024) {
        const ull q = ped[base + i];
        const int sv   = (int)(q & 0xFFFFull);
        const int dloc = (int)((q >> 16) & 255);
        const float evv = __uint_as_float((unsigned)(q >> 32));
        float z = es1[sv] + eds[dloc];
        float l = z > 0.f ? z : 0.2f * z;
        float e = __expf(l);
        atomicAdd(&den[dloc], e);
        const int pos = atomicAdd(&lcur[dloc], 1);
        wv[pos]    = e * evv;
        svl[pos]   = (unsigned short)sv;
        dlocl[pos] = (unsigned char)dloc;
        evl[pos]   = evv;
    }
    __syncthreads();

    // -------- phase B1: layer-1 aggregation (16 waves x 16 nodes) --------
    const int wid = t >> 6, lane = t & 63;
    const int grp = lane >> 2, sl = lane & 3;
    const int nloc = wid * 16 + grp;
    const int n = b * 256 + nloc;

    if (n < N) {
        const int dg   = degl[nloc];
        const int lbeg = lbase[nloc];

        float acc[16];
        #pragma unroll
        for (int k = 0; k < 16; ++k) acc[k] = 0.f;

        for (int j0 = 0; j0 < dg; j0 += 4) {
            #pragma unroll
            for (int ts = 0; ts < 4; ++ts) {
                const int jj  = j0 + ts;
                const int idx = lbeg + min(jj, dg - 1);
                const int svt = (int)svl[idx];
                float wt = wv[idx];
                wt = (jj < dg) ? wt : 0.f;
                const uint4 u = *(const uint4*)&h1[(size_t)svt * 16 + sl * 4];
                v2f fa = __builtin_amdgcn_cvt_pk_f32_fp8((int)u.x, false);
                v2f fb = __builtin_amdgcn_cvt_pk_f32_fp8((int)u.x, true);
                v2f fc = __builtin_amdgcn_cvt_pk_f32_fp8((int)u.y, false);
                v2f fd = __builtin_amdgcn_cvt_pk_f32_fp8((int)u.y, true);
                v2f fe = __builtin_amdgcn_cvt_pk_f32_fp8((int)u.z, false);
                v2f ff = __builtin_amdgcn_cvt_pk_f32_fp8((int)u.z, true);
                v2f fg = __builtin_amdgcn_cvt_pk_f32_fp8((int)u.w, false);
                v2f fh = __builtin_amdgcn_cvt_pk_f32_fp8((int)u.w, true);
                acc[0]  += wt * fa.x; acc[1]  += wt * fa.y;
                acc[2]  += wt * fb.x; acc[3]  += wt * fb.y;
                acc[4]  += wt * fc.x; acc[5]  += wt * fc.y;
                acc[6]  += wt * fd.x; acc[7]  += wt * fd.y;
                acc[8]  += wt * fe.x; acc[9]  += wt * fe.y;
                acc[10] += wt * ff.x; acc[11] += wt * ff.y;
                acc[12] += wt * fg.x; acc[13] += wt * fg.y;
                acc[14] += wt * fh.x; acc[15] += wt * fh.y;
            }
        }

        const float inv = 1.f / (den[nloc] + 1e-16f);

        const float4 b1v0 = *(const float4*)&b1[sl * 16];
        const float4 b1v1 = *(const float4*)&b1[sl * 16 + 4];
        const float4 b1v2 = *(const float4*)&b1[sl * 16 + 8];
        const float4 b1v3 = *(const float4*)&b1[sl * 16 + 12];

        float hid[16];
        hid[0]  = fmaxf(acc[0]  * inv + b1v0.x, 0.f);
        hid[1]  = fmaxf(acc[1]  * inv + b1v0.y, 0.f);
        hid[2]  = fmaxf(acc[2]  * inv + b1v0.z, 0.f);
        hid[3]  = fmaxf(acc[3]  * inv + b1v0.w, 0.f);
        hid[4]  = fmaxf(acc[4]  * inv + b1v1.x, 0.f);
        hid[5]  = fmaxf(acc[5]  * inv + b1v1.y, 0.f);
        hid[6]  = fmaxf(acc[6]  * inv + b1v1.z, 0.f);
        hid[7]  = fmaxf(acc[7]  * inv + b1v1.w, 0.f);
        hid[8]  = fmaxf(acc[8]  * inv + b1v2.x, 0.f);
        hid[9]  = fmaxf(acc[9]  * inv + b1v2.y, 0.f);
        hid[10] = fmaxf(acc[10] * inv + b1v2.z, 0.f);
        hid[11] = fmaxf(acc[11] * inv + b1v2.w, 0.f);
        hid[12] = fmaxf(acc[12] * inv + b1v3.x, 0.f);
        hid[13] = fmaxf(acc[13] * inv + b1v3.y, 0.f);
        hid[14] = fmaxf(acc[14] * inv + b1v3.z, 0.f);
        hid[15] = fmaxf(acc[15] * inv + b1v3.w, 0.f);

        float p[8];
        #pragma unroll
        for (int o = 0; o < 8; ++o) p[o] = 0.f;
        #pragma unroll
        for (int k = 0; k < 16; ++k) {
            const float4 wA = *(const float4*)&W2s[(sl * 16 + k) * 8];
            const float4 wB = *(const float4*)&W2s[(sl * 16 + k) * 8 + 4];
            p[0] += hid[k] * wA.x; p[1] += hid[k] * wA.y;
            p[2] += hid[k] * wA.z; p[3] += hid[k] * wA.w;
            p[4] += hid[k] * wB.x; p[5] += hid[k] * wB.y;
            p[6] += hid[k] * wB.z; p[7] += hid[k] * wB.w;
        }
        float s4[4];
        {
            const bool hi = (sl & 1);
            #pragma unroll
            for (int k = 0; k < 4; ++k) {
                float keep = hi ? p[k + 4] : p[k];
                float send = hi ? p[k]     : p[k + 4];
                s4[k] = keep + __shfl_xor(send, 1);
            }
        }
        float s2[2];
        {
            const bool hi = (sl & 2);
            #pragma unroll
            for (int k = 0; k < 2; ++k) {
                float keep = hi ? s4[k + 2] : s4[k];
                float send = hi ? s4[k]     : s4[k + 2];
                s2[k] = keep + __shfl_xor(send, 2);
            }
        }
        const int oo = 4 * (sl & 1) + 2 * ((sl >> 1) & 1);

        float tsv = s2[0] * a2s[oo] + s2[1] * a2s[oo + 1];
        float tdv = s2[0] * a2d[oo] + s2[1] * a2d[oo + 1];
        tsv += __shfl_xor(tsv, 1); tdv += __shfl_xor(tdv, 1);
        tsv += __shfl_xor(tsv, 2); tdv += __shfl_xor(tdv, 2);

        // h2/es2 cross the device barrier -> device-scope coherent stores
        F2U hv; hv.f = make_float2(s2[0], s2[1]);
        __hip_atomic_store((ull*)&h2[(size_t)n * 8 + oo], hv.u,
                           __ATOMIC_RELAXED, __HIP_MEMORY_SCOPE_AGENT);
        if (sl == 0) {
            __hip_atomic_store(&es2[n], tsv,
                               __ATOMIC_RELAXED, __HIP_MEMORY_SCOPE_AGENT);
            eds[nloc] = tdv;        // ed2 is block-local: LDS only
        }
    }
    __syncthreads();

    // -------- device barrier (all 196 blocks co-resident) --------
    if (t == 0) {
        __threadfence();
        atomicAdd(barrier_ctr, 1);
        while (__hip_atomic_load(barrier_ctr, __ATOMIC_ACQUIRE,
                                 __HIP_MEMORY_SCOPE_AGENT) < nbuck)
            __builtin_amdgcn_s_sleep(8);
    }
    __syncthreads();

    // -------- layer-2 weight recompute (linear over LDS records) --------
    if (t < 256) den[t] = 0.f;
    __syncthreads();
    for (int i = t; i < cnt; i += 1024) {
        const int sv = (int)svl[i];
        const int dl = (int)dlocl[i];
        const float es2v = __hip_atomic_load(&es2[sv], __ATOMIC_RELAXED,
                                             __HIP_MEMORY_SCOPE_AGENT);
        float z = es2v + eds[dl];
        float l = z > 0.f ? z : 0.2f * z;
        float q = __expf(l);
        atomicAdd(&den[dl], q);
        wv[i] = q * evl[i];
    }
    __syncthreads();

    // -------- phase B2: layer-2 aggregation + log_softmax --------
    if (n < N) {
        const int dg   = degl[nloc];
        const int lbeg = lbase[nloc];

        float a0 = 0.f, a1 = 0.f;

        for (int j0 = 0; j0 < dg; j0 += 4) {
            #pragma unroll
            for (int ts = 0; ts < 4; ++ts) {
                const int jj  = j0 + ts;
                const int idx = lbeg + min(jj, dg - 1);
                const int svt = (int)svl[idx];
                float wt = wv[idx];
                wt = (jj < dg) ? wt : 0.f;
                F2U hv;
                hv.u = __hip_atomic_load(
                    (const ull*)&h2[(size_t)svt * 8 + 2 * sl],
                    __ATOMIC_RELAXED, __HIP_MEMORY_SCOPE_AGENT);
                a0 += wt * hv.f.x;
                a1 += wt * hv.f.y;
            }
        }

        const float inv = 1.f / (den[nloc] + 1e-16f);
        float v0 = a0 * inv + b2[2 * sl];
        float v1 = a1 * inv + b2[2 * sl + 1];

        float vm = fmaxf(v0, v1);
        vm = fmaxf(vm, __shfl_xor(vm, 1));
        vm = fmaxf(vm, __shfl_xor(vm, 2));
        float s = __expf(v0 - vm) + __expf(v1 - vm);
        s += __shfl_xor(s, 1);
        s += __shfl_xor(s, 2);
        float lse = vm + logf(s);
        *(float2*)&out[(size_t)n * 8 + 2 * sl] = make_float2(v0 - lse, v1 - lse);
    }
}

// ---------------------------------------------------------------------------

extern "C" void kernel_launch(void* const* d_in, const int* in_sizes, int n_in,
                              void* d_out, int out_size, void* d_ws, size_t ws_size,
                              hipStream_t stream)
{
    const float* x   = (const float*)d_in[0];
    const int*   ei  = (const int*)d_in[1];
    const float* ev  = (const float*)d_in[2];
    const float* W1  = (const float*)d_in[3];
    const float* a1s = (const float*)d_in[4];
    const float* a1d = (const float*)d_in[5];
    const float* b1  = (const float*)d_in[6];
    const float* W2  = (const float*)d_in[7];
    const float* a2s = (const float*)d_in[8];
    const float* a2d = (const float*)d_in[9];
    const float* b2  = (const float*)d_in[10];
    float* out = (float*)d_out;

    const int N = in_sizes[0] / 64;
    const int E = in_sizes[2];
    const int* srcp = ei;
    const int* dstp = ei + E;
    const int nchunks = (E + CHUNK - 1) / CHUNK;
    const int ngemm   = (N + 63) / 64;
    const int nbuck   = (N + 255) / 256;

    // Workspace: ped 256*CAP ull | bcnt 256 | barrier_ctr 1 (padded to 64) |
    //            es1 N | ed1 N | es2 N | h1 16N uint | h2 8N float
    ull*   ped  = (ull*)d_ws;
    int*   bcnt = (int*)(ped + (size_t)NBKT * CAP);
    int*   bctr = bcnt + NBKT;                      // barrier counter
    float* es1  = (float*)(bctr + 64);
    float* ed1  = es1 + N;
    float* es2  = ed1 + N;
    unsigned* h1 = (unsigned*)(es2 + N);            // 16N uints (64N fp8)
    float* h2   = (float*)(h1 + (size_t)N * 16);    // 8N floats

    // zero bcnt + barrier counter in one memset
    hipMemsetAsync(bcnt, 0, (NBKT + 64) * sizeof(int), stream);

    // [edge partition || layer-1 GEMM] in one launch
    part_gemm_kernel<<<nchunks + ngemm, 256, 0, stream>>>(
        srcp, dstp, ev, bcnt, ped, E, nchunks,
        x, W1, a1s, a1d, h1, es1, ed1, N);

    // Layers 1+2 fused with device software barrier (all blocks co-resident)
    fused_l12_kernel<<<nbuck, 1024, 0, stream>>>(
        ped, bcnt, es1, ed1, h1, b1, W2, a2s, a2d,
        h2, es2, b2, out, N, nbuck, bctr);
}

// Round 11
// 147.353 us; speedup vs baseline: 1.0025x; 1.0025x over previous
//
#include <hip/hip_runtime.h>
#include <hip/hip_fp16.h>
#include <math.h>

// ---------------------------------------------------------------------------
// RGAT (2-layer graph attention) on MI355X — round 27.
// N=50000, E=800000 (avg deg 16), IN=64, HID=64, OUT=8.
// Round-27: r26's merged kernel with ONE fix. r26 rocprof: FETCH 23.4MB --
// the post-barrier __hip_atomic_load(AGENT) gathers bypass per-XCD L2, so
// every h2/es2 gather went to L3 uncached (the 51.5us). Coherence analysis:
// AGENT stores land at L3 (bypass writer L2); reader L2s are invalidated at
// kernel dispatch and never touch h2/es2 before the barrier -> plain cached
// loads after the barrier MUST miss to L3 once, then hit L2. So: AGENT
// stores kept, post-barrier loads now plain. Everything else identical to
// r26 (barrier, LDS-resident records surviving across layers, ed2 never
// leaving LDS). K1 (part_gemm) unchanged. h1 fp8 e4m3 (3.2MB, L2-resident).
// Pre-commit: if total >= 137.9 (r24) or absmax degrades, revert to r24.
// ---------------------------------------------------------------------------

#define CHUNK 4096
#define NBKT  256
#define CAP   6144   // per-bucket capacity (uniform random: 32-sigma margin)

typedef unsigned long long ull;
typedef float v2f __attribute__((ext_vector_type(2)));

union F2U { float2 f; ull u; };

struct PartSmem {
    int lhist[NBKT], lbase[NBKT], lcur[NBKT], gbase[NBKT];
    ull buf[CHUNK];
};
struct GemmSmem {
    float4 Wl[64 * 16];
    float  Xt[64 * 64];
};
union FusedSmem { PartSmem p; GemmSmem g; };

// ---------------- fused: edge partition (blocks < nchunks) + layer-1 GEMM ---

__global__ void __launch_bounds__(256) part_gemm_kernel(
    const int* __restrict__ src, const int* __restrict__ dst,
    const float* __restrict__ ev, int* __restrict__ bcnt,
    ull* __restrict__ ped, int E, int nchunks,
    const float* __restrict__ x, const float* __restrict__ W,
    const float* __restrict__ a_src, const float* __restrict__ a_dst,
    unsigned* __restrict__ h, float* __restrict__ es, float* __restrict__ ed,
    int N)
{
    __shared__ FusedSmem sm;
    const int t = threadIdx.x;

    if (blockIdx.x < nchunks) {
        // ---------------- partition path ----------------
        int e0 = blockIdx.x * CHUNK;
        int cnt = min(CHUNK, E - e0);
        sm.p.lhist[t] = 0;
        __syncthreads();
        for (int i = t; i < cnt; i += 256)
            atomicAdd(&sm.p.lhist[dst[e0 + i] >> 8], 1);
        __syncthreads();
        int myc = sm.p.lhist[t];
        sm.p.lbase[t] = myc;
        __syncthreads();
        for (int o = 1; o < 256; o <<= 1) {
            int add = (t >= o) ? sm.p.lbase[t - o] : 0;
            __syncthreads();
            sm.p.lbase[t] += add;
            __syncthreads();
        }
        int excl = sm.p.lbase[t] - myc;
        sm.p.gbase[t] = myc ? atomicAdd(&bcnt[t], myc) : 0;
        __syncthreads();
        sm.p.lbase[t] = excl;
        sm.p.lcur[t] = excl;
        __syncthreads();
        for (int i = t; i < cnt; i += 256) {
            int e = e0 + i;
            int d = dst[e];
            int b = d >> 8;
            unsigned p = (unsigned)src[e] | ((unsigned)(d & 255) << 16)
                       | ((unsigned)b << 24);
            ull q = (ull)p | ((ull)__float_as_uint(ev[e]) << 32);
            int r = atomicAdd(&sm.p.lcur[b], 1);
            sm.p.buf[r] = q;
        }
        __syncthreads();
        for (int i = t; i < cnt; i += 256) {
            ull q = sm.p.buf[i];
            int b = (int)((q >> 24) & 255);
            ped[(size_t)b * CAP + sm.p.gbase[b] + i - sm.p.lbase[b]] = q;
        }
        return;
    }

    // ---------------- GEMM path ----------------
    const int n0 = (blockIdx.x - nchunks) * 64;

    #pragma unroll
    for (int i = 0; i < 4; ++i)
        sm.g.Wl[t + i * 256] = ((const float4*)W)[t + i * 256];

    #pragma unroll
    for (int i = 0; i < 4; ++i) {
        int f   = t + i * 256;
        int row = f >> 4, kq = f & 15;
        int grow = n0 + row;
        float4 v = make_float4(0.f, 0.f, 0.f, 0.f);
        if (grow < N) v = ((const float4*)x)[(size_t)grow * 16 + kq];
        int rs = row ^ ((kq & 3) << 2);
        sm.g.Xt[(kq * 4 + 0) * 64 + rs] = v.x;
        sm.g.Xt[(kq * 4 + 1) * 64 + rs] = v.y;
        sm.g.Xt[(kq * 4 + 2) * 64 + rs] = v.z;
        sm.g.Xt[(kq * 4 + 3) * 64 + rs] = v.w;
    }

    const int tx = t & 15;
    const int ty = t >> 4;
    const float4 asv = ((const float4*)a_src)[tx];
    const float4 adv = ((const float4*)a_dst)[tx];
    __syncthreads();

    float4 acc0 = make_float4(0.f,0.f,0.f,0.f);
    float4 acc1 = make_float4(0.f,0.f,0.f,0.f);
    float4 acc2 = make_float4(0.f,0.f,0.f,0.f);
    float4 acc3 = make_float4(0.f,0.f,0.f,0.f);

    #pragma unroll 8
    for (int k = 0; k < 64; ++k) {
        int swz = (k >> 2) & 3;
        const float4 xr = *(const float4*)&sm.g.Xt[k * 64 + ((ty ^ swz) << 2)];
        const float4 wv = sm.g.Wl[k * 16 + tx];
        acc0.x += xr.x * wv.x; acc0.y += xr.x * wv.y;
        acc0.z += xr.x * wv.z; acc0.w += xr.x * wv.w;
        acc1.x += xr.y * wv.x; acc1.y += xr.y * wv.y;
        acc1.z += xr.y * wv.z; acc1.w += xr.y * wv.w;
        acc2.x += xr.z * wv.x; acc2.y += xr.z * wv.y;
        acc2.z += xr.z * wv.z; acc2.w += xr.z * wv.w;
        acc3.x += xr.w * wv.x; acc3.y += xr.w * wv.y;
        acc3.z += xr.w * wv.z; acc3.w += xr.w * wv.w;
    }

    float4 accs[4] = {acc0, acc1, acc2, acc3};
    #pragma unroll
    for (int r = 0; r < 4; ++r) {
        int grow = n0 + ty * 4 + r;
        float4 a = accs[r];
        if (grow < N) {
            int lo = __builtin_amdgcn_cvt_pk_fp8_f32(a.x, a.y, 0, false);
            int pk = __builtin_amdgcn_cvt_pk_fp8_f32(a.z, a.w, lo, true);
            h[(size_t)grow * 16 + tx] = (unsigned)pk;
        }
        float ps = a.x * asv.x + a.y * asv.y + a.z * asv.z + a.w * asv.w;
        float pd = a.x * adv.x + a.y * adv.y + a.z * adv.z + a.w * adv.w;
        #pragma unroll
        for (int o = 8; o > 0; o >>= 1) {
            ps += __shfl_xor(ps, o);
            pd += __shfl_xor(pd, o);
        }
        if (tx == 0 && grow < N) { es[grow] = ps; ed[grow] = pd; }
    }
}

// ---------------- fused layers 1+2: CSR (LDS) + agg64 + BARRIER + agg8 ------

__global__ void __launch_bounds__(1024) fused_l12_kernel(
    const ull* __restrict__ ped, const int* __restrict__ bcnt,
    const float* __restrict__ es1, const float* __restrict__ ed1,
    const unsigned* __restrict__ h1, const float* __restrict__ b1,
    const float* __restrict__ W2, const float* __restrict__ a2s,
    const float* __restrict__ a2d, float* __restrict__ h2,
    float* __restrict__ es2, const float* __restrict__ b2,
    float* __restrict__ out, int N, int nbuck, int* __restrict__ barrier_ctr)
{
    __shared__ int    lhist[256], lbase[256], lcur[256], degl[256];
    __shared__ float  den[256], eds[256];
    __shared__ float  W2s[64 * 8];
    __shared__ float  wv[CAP];
    __shared__ float  evl[CAP];
    __shared__ unsigned short svl[CAP];
    __shared__ unsigned char  dlocl[CAP];

    const int b = blockIdx.x, t = threadIdx.x;
    const int cnt = min(bcnt[b], CAP);
    const size_t base = (size_t)b * CAP;

    if (t < 256) {
        const int nodeT = b * 256 + t;
        lhist[t] = 0;
        den[t] = 0.f;
        eds[t] = (nodeT < N) ? ed1[nodeT] : 0.f;
    }
    if (t < 128) ((float4*)W2s)[t] = ((const float4*)W2)[t];
    __syncthreads();

    // -------- CSR build in LDS --------
    for (int i = t; i < cnt; i += 1024)
        atomicAdd(&lhist[(int)((ped[base + i] >> 16) & 255)], 1);
    __syncthreads();
    int myc = (t < 256) ? lhist[t] : 0;
    if (t < 256) lbase[t] = myc;
    __syncthreads();
    for (int o = 1; o < 256; o <<= 1) {
        int add = (t >= o && t < 256) ? lbase[t - o] : 0;
        __syncthreads();
        if (t < 256) lbase[t] += add;
        __syncthreads();
    }
    if (t < 256) {
        lcur[t] = lbase[t] - myc;
        degl[t] = myc;
    }
    __syncthreads();
    if (t < 256) lbase[t] -= myc;       // lbase := exclusive offsets
    __syncthreads();

    // scatter + layer-1 weight precompute (one exp per edge)
    for (int i = t; i < cnt; i += 1024) {
        const ull q = ped[base + i];
        const int sv   = (int)(q & 0xFFFFull);
        const int dloc = (int)((q >> 16) & 255);
        const float evv = __uint_as_float((unsigned)(q >> 32));
        float z = es1[sv] + eds[dloc];
        float l = z > 0.f ? z : 0.2f * z;
        float e = __expf(l);
        atomicAdd(&den[dloc], e);
        const int pos = atomicAdd(&lcur[dloc], 1);
        wv[pos]    = e * evv;
        svl[pos]   = (unsigned short)sv;
        dlocl[pos] = (unsigned char)dloc;
        evl[pos]   = evv;
    }
    __syncthreads();

    // -------- phase B1: layer-1 aggregation (16 waves x 16 nodes) --------
    const int wid = t >> 6, lane = t & 63;
    const int grp = lane >> 2, sl = lane & 3;
    const int nloc = wid * 16 + grp;
    const int n = b * 256 + nloc;

    if (n < N) {
        const int dg   = degl[nloc];
        const int lbeg = lbase[nloc];

        float acc[16];
        #pragma unroll
        for (int k = 0; k < 16; ++k) acc[k] = 0.f;

        for (int j0 = 0; j0 < dg; j0 += 4) {
            #pragma unroll
            for (int ts = 0; ts < 4; ++ts) {
                const int jj  = j0 + ts;
                const int idx = lbeg + min(jj, dg - 1);
                const int svt = (int)svl[idx];
                float wt = wv[idx];
                wt = (jj < dg) ? wt : 0.f;
                const uint4 u = *(const uint4*)&h1[(size_t)svt * 16 + sl * 4];
                v2f fa = __builtin_amdgcn_cvt_pk_f32_fp8((int)u.x, false);
                v2f fb = __builtin_amdgcn_cvt_pk_f32_fp8((int)u.x, true);
                v2f fc = __builtin_amdgcn_cvt_pk_f32_fp8((int)u.y, false);
                v2f fd = __builtin_amdgcn_cvt_pk_f32_fp8((int)u.y, true);
                v2f fe = __builtin_amdgcn_cvt_pk_f32_fp8((int)u.z, false);
                v2f ff = __builtin_amdgcn_cvt_pk_f32_fp8((int)u.z, true);
                v2f fg = __builtin_amdgcn_cvt_pk_f32_fp8((int)u.w, false);
                v2f fh = __builtin_amdgcn_cvt_pk_f32_fp8((int)u.w, true);
                acc[0]  += wt * fa.x; acc[1]  += wt * fa.y;
                acc[2]  += wt * fb.x; acc[3]  += wt * fb.y;
                acc[4]  += wt * fc.x; acc[5]  += wt * fc.y;
                acc[6]  += wt * fd.x; acc[7]  += wt * fd.y;
                acc[8]  += wt * fe.x; acc[9]  += wt * fe.y;
                acc[10] += wt * ff.x; acc[11] += wt * ff.y;
                acc[12] += wt * fg.x; acc[13] += wt * fg.y;
                acc[14] += wt * fh.x; acc[15] += wt * fh.y;
            }
        }

        const float inv = 1.f / (den[nloc] + 1e-16f);

        const float4 b1v0 = *(const float4*)&b1[sl * 16];
        const float4 b1v1 = *(const float4*)&b1[sl * 16 + 4];
        const float4 b1v2 = *(const float4*)&b1[sl * 16 + 8];
        const float4 b1v3 = *(const float4*)&b1[sl * 16 + 12];

        float hid[16];
        hid[0]  = fmaxf(acc[0]  * inv + b1v0.x, 0.f);
        hid[1]  = fmaxf(acc[1]  * inv + b1v0.y, 0.f);
        hid[2]  = fmaxf(acc[2]  * inv + b1v0.z, 0.f);
        hid[3]  = fmaxf(acc[3]  * inv + b1v0.w, 0.f);
        hid[4]  = fmaxf(acc[4]  * inv + b1v1.x, 0.f);
        hid[5]  = fmaxf(acc[5]  * inv + b1v1.y, 0.f);
        hid[6]  = fmaxf(acc[6]  * inv + b1v1.z, 0.f);
        hid[7]  = fmaxf(acc[7]  * inv + b1v1.w, 0.f);
        hid[8]  = fmaxf(acc[8]  * inv + b1v2.x, 0.f);
        hid[9]  = fmaxf(acc[9]  * inv + b1v2.y, 0.f);
        hid[10] = fmaxf(acc[10] * inv + b1v2.z, 0.f);
        hid[11] = fmaxf(acc[11] * inv + b1v2.w, 0.f);
        hid[12] = fmaxf(acc[12] * inv + b1v3.x, 0.f);
        hid[13] = fmaxf(acc[13] * inv + b1v3.y, 0.f);
        hid[14] = fmaxf(acc[14] * inv + b1v3.z, 0.f);
        hid[15] = fmaxf(acc[15] * inv + b1v3.w, 0.f);

        float p[8];
        #pragma unroll
        for (int o = 0; o < 8; ++o) p[o] = 0.f;
        #pragma unroll
        for (int k = 0; k < 16; ++k) {
            const float4 wA = *(const float4*)&W2s[(sl * 16 + k) * 8];
            const float4 wB = *(const float4*)&W2s[(sl * 16 + k) * 8 + 4];
            p[0] += hid[k] * wA.x; p[1] += hid[k] * wA.y;
            p[2] += hid[k] * wA.z; p[3] += hid[k] * wA.w;
            p[4] += hid[k] * wB.x; p[5] += hid[k] * wB.y;
            p[6] += hid[k] * wB.z; p[7] += hid[k] * wB.w;
        }
        float s4[4];
        {
            const bool hi = (sl & 1);
            #pragma unroll
            for (int k = 0; k < 4; ++k) {
                float keep = hi ? p[k + 4] : p[k];
                float send = hi ? p[k]     : p[k + 4];
                s4[k] = keep + __shfl_xor(send, 1);
            }
        }
        float s2[2];
        {
            const bool hi = (sl & 2);
            #pragma unroll
            for (int k = 0; k < 2; ++k) {
                float keep = hi ? s4[k + 2] : s4[k];
                float send = hi ? s4[k]     : s4[k + 2];
                s2[k] = keep + __shfl_xor(send, 2);
            }
        }
        const int oo = 4 * (sl & 1) + 2 * ((sl >> 1) & 1);

        float tsv = s2[0] * a2s[oo] + s2[1] * a2s[oo + 1];
        float tdv = s2[0] * a2d[oo] + s2[1] * a2d[oo + 1];
        tsv += __shfl_xor(tsv, 1); tdv += __shfl_xor(tdv, 1);
        tsv += __shfl_xor(tsv, 2); tdv += __shfl_xor(tdv, 2);

        // h2/es2 cross the device barrier -> write-through (bypass local L2)
        F2U hv; hv.f = make_float2(s2[0], s2[1]);
        __hip_atomic_store((ull*)&h2[(size_t)n * 8 + oo], hv.u,
                           __ATOMIC_RELAXED, __HIP_MEMORY_SCOPE_AGENT);
        if (sl == 0) {
            __hip_atomic_store(&es2[n], tsv,
                               __ATOMIC_RELAXED, __HIP_MEMORY_SCOPE_AGENT);
            eds[nloc] = tdv;        // ed2 is block-local: LDS only
        }
    }
    __syncthreads();

    // -------- device barrier (all 196 blocks co-resident) --------
    if (t == 0) {
        __threadfence();
        atomicAdd(barrier_ctr, 1);
        while (__hip_atomic_load(barrier_ctr, __ATOMIC_ACQUIRE,
                                 __HIP_MEMORY_SCOPE_AGENT) < nbuck)
            __builtin_amdgcn_s_sleep(8);
    }
    __syncthreads();

    // -------- layer-2 weight recompute (linear over LDS records) --------
    // PLAIN loads: reader L2s never cached es2/h2 this kernel (invalidated
    // at dispatch, first touch is here), writers bypassed their L2 -> the
    // L3 copy is authoritative and a cached load is safe + L2-cacheable.
    if (t < 256) den[t] = 0.f;
    __syncthreads();
    for (int i = t; i < cnt; i += 1024) {
        const int sv = (int)svl[i];
        const int dl = (int)dlocl[i];
        float z = es2[sv] + eds[dl];
        float l = z > 0.f ? z : 0.2f * z;
        float q = __expf(l);
        atomicAdd(&den[dl], q);
        wv[i] = q * evl[i];
    }
    __syncthreads();

    // -------- phase B2: layer-2 aggregation + log_softmax --------
    if (n < N) {
        const int dg   = degl[nloc];
        const int lbeg = lbase[nloc];

        float a0 = 0.f, a1 = 0.f;

        for (int j0 = 0; j0 < dg; j0 += 4) {
            #pragma unroll
            for (int ts = 0; ts < 4; ++ts) {
                const int jj  = j0 + ts;
                const int idx = lbeg + min(jj, dg - 1);
                const int svt = (int)svl[idx];
                float wt = wv[idx];
                wt = (jj < dg) ? wt : 0.f;
                const float2 f = *(const float2*)&h2[(size_t)svt * 8 + 2 * sl];
                a0 += wt * f.x;
                a1 += wt * f.y;
            }
        }

        const float inv = 1.f / (den[nloc] + 1e-16f);
        float v0 = a0 * inv + b2[2 * sl];
        float v1 = a1 * inv + b2[2 * sl + 1];

        float vm = fmaxf(v0, v1);
        vm = fmaxf(vm, __shfl_xor(vm, 1));
        vm = fmaxf(vm, __shfl_xor(vm, 2));
        float s = __expf(v0 - vm) + __expf(v1 - vm);
        s += __shfl_xor(s, 1);
        s += __shfl_xor(s, 2);
        float lse = vm + logf(s);
        *(float2*)&out[(size_t)n * 8 + 2 * sl] = make_float2(v0 - lse, v1 - lse);
    }
}

// ---------------------------------------------------------------------------

extern "C" void kernel_launch(void* const* d_in, const int* in_sizes, int n_in,
                              void* d_out, int out_size, void* d_ws, size_t ws_size,
                              hipStream_t stream)
{
    const float* x   = (const float*)d_in[0];
    const int*   ei  = (const int*)d_in[1];
    const float* ev  = (const float*)d_in[2];
    const float* W1  = (const float*)d_in[3];
    const float* a1s = (const float*)d_in[4];
    const float* a1d = (const float*)d_in[5];
    const float* b1  = (const float*)d_in[6];
    const float* W2  = (const float*)d_in[7];
    const float* a2s = (const float*)d_in[8];
    const float* a2d = (const float*)d_in[9];
    const float* b2  = (const float*)d_in[10];
    float* out = (float*)d_out;

    const int N = in_sizes[0] / 64;
    const int E = in_sizes[2];
    const int* srcp = ei;
    const int* dstp = ei + E;
    const int nchunks = (E + CHUNK - 1) / CHUNK;
    const int ngemm   = (N + 63) / 64;
    const int nbuck   = (N + 255) / 256;

    // Workspace: ped 256*CAP ull | bcnt 256 | barrier_ctr (padded 64) |
    //            es1 N | ed1 N | es2 N | h1 16N uint | h2 8N float
    ull*   ped  = (ull*)d_ws;
    int*   bcnt = (int*)(ped + (size_t)NBKT * CAP);
    int*   bctr = bcnt + NBKT;                      // barrier counter
    float* es1  = (float*)(bctr + 64);
    float* ed1  = es1 + N;
    float* es2  = ed1 + N;
    unsigned* h1 = (unsigned*)(es2 + N);            // 16N uints (64N fp8)
    float* h2   = (float*)(h1 + (size_t)N * 16);    // 8N floats

    // zero bcnt + barrier counter in one memset
    hipMemsetAsync(bcnt, 0, (NBKT + 64) * sizeof(int), stream);

    // [edge partition || layer-1 GEMM] in one launch
    part_gemm_kernel<<<nchunks + ngemm, 256, 0, stream>>>(
        srcp, dstp, ev, bcnt, ped, E, nchunks,
        x, W1, a1s, a1d, h1, es1, ed1, N);

    // Layers 1+2 fused with device software barrier (all blocks co-resident)
    fused_l12_kernel<<<nbuck, 1024, 0, stream>>>(
        ped, bcnt, es1, ed1, h1, b1, W2, a2s, a2d,
        h2, es2, b2, out, N, nbuck, bctr);
}

// Round 12
// 135.982 us; speedup vs baseline: 1.0863x; 1.0836x over previous
//
#include <hip/hip_runtime.h>
#include <hip/hip_fp16.h>
#include <math.h>

// ---------------------------------------------------------------------------
// RGAT (2-layer graph attention) on MI355X — round 28.
// N=50000, E=800000 (avg deg 16), IN=64, HID=64, OUT=8.
// Round-28: r24 structure (best, 137.9us) + full-machine bucketing. r26/r27
// proved the barrier-fused variant is slower than split K2+K3 (51.5 vs ~42us)
// -> reverted per pre-commitment. The one measured fixable inefficiency in
// r24: K2/K3 ran 196 blocks on 256 CUs (23% idle; grid < CU count). Bucket
// map changed from b=d>>8 (196 buckets) to b=d&255 (256 buckets, ~195 nodes
// each, node n lives in bucket n&255 at slot dloc=n>>8<=195, still fits the
// 8-bit record field). CAP 6144->4096 (mean 3125, >15-sigma margin), K2 LDS
// ~32KB. Both per-bucket kernels now fill all 256 CUs. All else = r24:
// 1024-thr blocks, LDS-resident records, lean no-shfl hot loops, h1 fp8.
// ---------------------------------------------------------------------------

#define CHUNK 4096
#define NBKT  256
#define CAP   4096   // per-bucket capacity (mean 3125, >15-sigma margin)

typedef unsigned long long ull;
typedef float v2f __attribute__((ext_vector_type(2)));

struct PartSmem {
    int lhist[NBKT], lbase[NBKT], lcur[NBKT], gbase[NBKT];
    ull buf[CHUNK];
};
struct GemmSmem {
    float4 Wl[64 * 16];
    float  Xt[64 * 64];
};
union FusedSmem { PartSmem p; GemmSmem g; };

// ---------------- fused: edge partition (blocks < nchunks) + layer-1 GEMM ---

__global__ void __launch_bounds__(256) part_gemm_kernel(
    const int* __restrict__ src, const int* __restrict__ dst,
    const float* __restrict__ ev, int* __restrict__ bcnt,
    ull* __restrict__ ped, int E, int nchunks,
    const float* __restrict__ x, const float* __restrict__ W,
    const float* __restrict__ a_src, const float* __restrict__ a_dst,
    unsigned* __restrict__ h, float* __restrict__ es, float* __restrict__ ed,
    int N)
{
    __shared__ FusedSmem sm;
    const int t = threadIdx.x;

    if (blockIdx.x < nchunks) {
        // ---------------- partition path ----------------
        int e0 = blockIdx.x * CHUNK;
        int cnt = min(CHUNK, E - e0);
        sm.p.lhist[t] = 0;
        __syncthreads();
        for (int i = t; i < cnt; i += 256)
            atomicAdd(&sm.p.lhist[dst[e0 + i] & 255], 1);
        __syncthreads();
        int myc = sm.p.lhist[t];
        sm.p.lbase[t] = myc;
        __syncthreads();
        for (int o = 1; o < 256; o <<= 1) {
            int add = (t >= o) ? sm.p.lbase[t - o] : 0;
            __syncthreads();
            sm.p.lbase[t] += add;
            __syncthreads();
        }
        int excl = sm.p.lbase[t] - myc;
        sm.p.gbase[t] = myc ? atomicAdd(&bcnt[t], myc) : 0;
        __syncthreads();
        sm.p.lbase[t] = excl;
        sm.p.lcur[t] = excl;
        __syncthreads();
        for (int i = t; i < cnt; i += 256) {
            int e = e0 + i;
            int d = dst[e];
            int b = d & 255;
            unsigned p = (unsigned)src[e] | ((unsigned)(d >> 8) << 16)
                       | ((unsigned)b << 24);
            ull q = (ull)p | ((ull)__float_as_uint(ev[e]) << 32);
            int r = atomicAdd(&sm.p.lcur[b], 1);
            sm.p.buf[r] = q;
        }
        __syncthreads();
        for (int i = t; i < cnt; i += 256) {
            ull q = sm.p.buf[i];
            int b = (int)((q >> 24) & 255);
            ped[(size_t)b * CAP + sm.p.gbase[b] + i - sm.p.lbase[b]] = q;
        }
        return;
    }

    // ---------------- GEMM path ----------------
    const int n0 = (blockIdx.x - nchunks) * 64;

    #pragma unroll
    for (int i = 0; i < 4; ++i)
        sm.g.Wl[t + i * 256] = ((const float4*)W)[t + i * 256];

    #pragma unroll
    for (int i = 0; i < 4; ++i) {
        int f   = t + i * 256;
        int row = f >> 4, kq = f & 15;
        int grow = n0 + row;
        float4 v = make_float4(0.f, 0.f, 0.f, 0.f);
        if (grow < N) v = ((const float4*)x)[(size_t)grow * 16 + kq];
        int rs = row ^ ((kq & 3) << 2);
        sm.g.Xt[(kq * 4 + 0) * 64 + rs] = v.x;
        sm.g.Xt[(kq * 4 + 1) * 64 + rs] = v.y;
        sm.g.Xt[(kq * 4 + 2) * 64 + rs] = v.z;
        sm.g.Xt[(kq * 4 + 3) * 64 + rs] = v.w;
    }

    const int tx = t & 15;
    const int ty = t >> 4;
    const float4 asv = ((const float4*)a_src)[tx];
    const float4 adv = ((const float4*)a_dst)[tx];
    __syncthreads();

    float4 acc0 = make_float4(0.f,0.f,0.f,0.f);
    float4 acc1 = make_float4(0.f,0.f,0.f,0.f);
    float4 acc2 = make_float4(0.f,0.f,0.f,0.f);
    float4 acc3 = make_float4(0.f,0.f,0.f,0.f);

    #pragma unroll 8
    for (int k = 0; k < 64; ++k) {
        int swz = (k >> 2) & 3;
        const float4 xr = *(const float4*)&sm.g.Xt[k * 64 + ((ty ^ swz) << 2)];
        const float4 wv = sm.g.Wl[k * 16 + tx];
        acc0.x += xr.x * wv.x; acc0.y += xr.x * wv.y;
        acc0.z += xr.x * wv.z; acc0.w += xr.x * wv.w;
        acc1.x += xr.y * wv.x; acc1.y += xr.y * wv.y;
        acc1.z += xr.y * wv.z; acc1.w += xr.y * wv.w;
        acc2.x += xr.z * wv.x; acc2.y += xr.z * wv.y;
        acc2.z += xr.z * wv.z; acc2.w += xr.z * wv.w;
        acc3.x += xr.w * wv.x; acc3.y += xr.w * wv.y;
        acc3.z += xr.w * wv.z; acc3.w += xr.w * wv.w;
    }

    float4 accs[4] = {acc0, acc1, acc2, acc3};
    #pragma unroll
    for (int r = 0; r < 4; ++r) {
        int grow = n0 + ty * 4 + r;
        float4 a = accs[r];
        if (grow < N) {
            int lo = __builtin_amdgcn_cvt_pk_fp8_f32(a.x, a.y, 0, false);
            int pk = __builtin_amdgcn_cvt_pk_fp8_f32(a.z, a.w, lo, true);
            h[(size_t)grow * 16 + tx] = (unsigned)pk;
        }
        float ps = a.x * asv.x + a.y * asv.y + a.z * asv.z + a.w * asv.w;
        float pd = a.x * adv.x + a.y * adv.y + a.z * adv.z + a.w * adv.w;
        #pragma unroll
        for (int o = 8; o > 0; o >>= 1) {
            ps += __shfl_xor(ps, o);
            pd += __shfl_xor(pd, o);
        }
        if (tx == 0 && grow < N) { es[grow] = ps; ed[grow] = pd; }
    }
}

// ---------------- fused: CSR finalize + w1 precompute + agg64 (1024 thr) ----
// One block per bucket b (nodes n with n&255==b, slot dloc=n>>8, <=196
// nodes). Phase A: hist+scan; scatter computes q1 once per edge; sv/w1
// staged in LDS; den1 in LDS; csre written for K3. Phase B: 16 waves x 16
// slots; hot loop: LDS record (free 4-lane broadcast) -> h1 gather -> FMA.

__global__ void __launch_bounds__(1024) csrw_agg64_kernel(
    const ull* __restrict__ ped, const int* __restrict__ bcnt,
    const float* __restrict__ es1, const float* __restrict__ ed1,
    int* __restrict__ off, int* __restrict__ deg, ull* __restrict__ csre,
    const unsigned* __restrict__ h1, const float* __restrict__ b1,
    const float* __restrict__ W2, const float* __restrict__ a2s,
    const float* __restrict__ a2d, float* __restrict__ h2,
    float* __restrict__ es2, float* __restrict__ ed2, int N)
{
    __shared__ int    lhist[256], lbase[256], lcur[256], degl[256];
    __shared__ float  den1[256], eds[256];
    __shared__ float  W2s[64 * 8];
    __shared__ float  w1v[CAP];
    __shared__ unsigned short svl[CAP];

    const int b = blockIdx.x, t = threadIdx.x;
    const int cnt = min(bcnt[b], CAP);
    const size_t base = (size_t)b * CAP;

    if (t < 256) {
        const int nodeT = t * 256 + b;      // slot t of bucket b
        lhist[t] = 0;
        den1[t] = 0.f;
        eds[t] = (nodeT < N) ? ed1[nodeT] : 0.f;
    }
    if (t < 128) ((float4*)W2s)[t] = ((const float4*)W2)[t];
    __syncthreads();

    for (int i = t; i < cnt; i += 1024)
        atomicAdd(&lhist[(int)((ped[base + i] >> 16) & 255)], 1);
    __syncthreads();
    int myc = (t < 256) ? lhist[t] : 0;
    if (t < 256) lbase[t] = myc;
    __syncthreads();
    for (int o = 1; o < 256; o <<= 1) {
        int add = (t >= o && t < 256) ? lbase[t - o] : 0;
        __syncthreads();
        if (t < 256) lbase[t] += add;
        __syncthreads();
    }
    if (t < 256) {
        const int excl = lbase[t] - myc;
        const int nodeT = t * 256 + b;
        lcur[t] = excl;
        degl[t] = myc;
        if (nodeT < N) { off[nodeT] = (int)base + excl; deg[nodeT] = myc; }
    }
    __syncthreads();
    if (t < 256) lbase[t] -= myc;       // lbase := exclusive offsets
    __syncthreads();

    // scatter + weight precompute (one exp per edge)
    for (int i = t; i < cnt; i += 1024) {
        const ull q = ped[base + i];
        const int sv   = (int)(q & 0xFFFFull);
        const int dloc = (int)((q >> 16) & 255);
        const float evv = __uint_as_float((unsigned)(q >> 32));
        float z = es1[sv] + eds[dloc];
        float l = z > 0.f ? z : 0.2f * z;
        float e = __expf(l);
        atomicAdd(&den1[dloc], e);
        const int pos = atomicAdd(&lcur[dloc], 1);
        w1v[pos] = e * evv;
        svl[pos] = (unsigned short)sv;
        csre[base + pos] = (q & 0xFFFFFFFF00000000ull)
                         | ((ull)(unsigned)(dloc << 16)) | (ull)(unsigned)sv;
    }
    __syncthreads();

    // ---------------- phase B: aggregation (16 waves x 16 slots) ---------
    const int wid = t >> 6, lane = t & 63;
    const int grp = lane >> 2, sl = lane & 3;
    const int nloc = wid * 16 + grp;
    const int n = nloc * 256 + b;
    if (n >= N) return;

    const int dg   = degl[nloc];
    const int lbeg = lbase[nloc];

    float acc[16];
    #pragma unroll
    for (int k = 0; k < 16; ++k) acc[k] = 0.f;

    for (int j0 = 0; j0 < dg; j0 += 4) {
        #pragma unroll
        for (int ts = 0; ts < 4; ++ts) {
            const int jj  = j0 + ts;
            const int idx = lbeg + min(jj, dg - 1);
            const int svt = (int)svl[idx];
            float wt = w1v[idx];
            wt = (jj < dg) ? wt : 0.f;
            const uint4 u = *(const uint4*)&h1[(size_t)svt * 16 + sl * 4];
            v2f fa = __builtin_amdgcn_cvt_pk_f32_fp8((int)u.x, false);
            v2f fb = __builtin_amdgcn_cvt_pk_f32_fp8((int)u.x, true);
            v2f fc = __builtin_amdgcn_cvt_pk_f32_fp8((int)u.y, false);
            v2f fd = __builtin_amdgcn_cvt_pk_f32_fp8((int)u.y, true);
            v2f fe = __builtin_amdgcn_cvt_pk_f32_fp8((int)u.z, false);
            v2f ff = __builtin_amdgcn_cvt_pk_f32_fp8((int)u.z, true);
            v2f fg = __builtin_amdgcn_cvt_pk_f32_fp8((int)u.w, false);
            v2f fh = __builtin_amdgcn_cvt_pk_f32_fp8((int)u.w, true);
            acc[0]  += wt * fa.x; acc[1]  += wt * fa.y;
            acc[2]  += wt * fb.x; acc[3]  += wt * fb.y;
            acc[4]  += wt * fc.x; acc[5]  += wt * fc.y;
            acc[6]  += wt * fd.x; acc[7]  += wt * fd.y;
            acc[8]  += wt * fe.x; acc[9]  += wt * fe.y;
            acc[10] += wt * ff.x; acc[11] += wt * ff.y;
            acc[12] += wt * fg.x; acc[13] += wt * fg.y;
            acc[14] += wt * fh.x; acc[15] += wt * fh.y;
        }
    }

    const float inv = 1.f / (den1[nloc] + 1e-16f);

    const float4 b1v0 = *(const float4*)&b1[sl * 16];
    const float4 b1v1 = *(const float4*)&b1[sl * 16 + 4];
    const float4 b1v2 = *(const float4*)&b1[sl * 16 + 8];
    const float4 b1v3 = *(const float4*)&b1[sl * 16 + 12];

    float hid[16];
    hid[0]  = fmaxf(acc[0]  * inv + b1v0.x, 0.f);
    hid[1]  = fmaxf(acc[1]  * inv + b1v0.y, 0.f);
    hid[2]  = fmaxf(acc[2]  * inv + b1v0.z, 0.f);
    hid[3]  = fmaxf(acc[3]  * inv + b1v0.w, 0.f);
    hid[4]  = fmaxf(acc[4]  * inv + b1v1.x, 0.f);
    hid[5]  = fmaxf(acc[5]  * inv + b1v1.y, 0.f);
    hid[6]  = fmaxf(acc[6]  * inv + b1v1.z, 0.f);
    hid[7]  = fmaxf(acc[7]  * inv + b1v1.w, 0.f);
    hid[8]  = fmaxf(acc[8]  * inv + b1v2.x, 0.f);
    hid[9]  = fmaxf(acc[9]  * inv + b1v2.y, 0.f);
    hid[10] = fmaxf(acc[10] * inv + b1v2.z, 0.f);
    hid[11] = fmaxf(acc[11] * inv + b1v2.w, 0.f);
    hid[12] = fmaxf(acc[12] * inv + b1v3.x, 0.f);
    hid[13] = fmaxf(acc[13] * inv + b1v3.y, 0.f);
    hid[14] = fmaxf(acc[14] * inv + b1v3.z, 0.f);
    hid[15] = fmaxf(acc[15] * inv + b1v3.w, 0.f);

    float p[8];
    #pragma unroll
    for (int o = 0; o < 8; ++o) p[o] = 0.f;
    #pragma unroll
    for (int k = 0; k < 16; ++k) {
        const float4 wA = *(const float4*)&W2s[(sl * 16 + k) * 8];
        const float4 wB = *(const float4*)&W2s[(sl * 16 + k) * 8 + 4];
        p[0] += hid[k] * wA.x; p[1] += hid[k] * wA.y;
        p[2] += hid[k] * wA.z; p[3] += hid[k] * wA.w;
        p[4] += hid[k] * wB.x; p[5] += hid[k] * wB.y;
        p[6] += hid[k] * wB.z; p[7] += hid[k] * wB.w;
    }
    float s4[4];
    {
        const bool hi = (sl & 1);
        #pragma unroll
        for (int k = 0; k < 4; ++k) {
            float keep = hi ? p[k + 4] : p[k];
            float send = hi ? p[k]     : p[k + 4];
            s4[k] = keep + __shfl_xor(send, 1);
        }
    }
    float s2[2];
    {
        const bool hi = (sl & 2);
        #pragma unroll
        for (int k = 0; k < 2; ++k) {
            float keep = hi ? s4[k + 2] : s4[k];
            float send = hi ? s4[k]     : s4[k + 2];
            s2[k] = keep + __shfl_xor(send, 2);
        }
    }
    const int oo = 4 * (sl & 1) + 2 * ((sl >> 1) & 1);

    float tsv = s2[0] * a2s[oo] + s2[1] * a2s[oo + 1];
    float tdv = s2[0] * a2d[oo] + s2[1] * a2d[oo + 1];
    tsv += __shfl_xor(tsv, 1); tdv += __shfl_xor(tdv, 1);
    tsv += __shfl_xor(tsv, 2); tdv += __shfl_xor(tdv, 2);

    *(float2*)&h2[(size_t)n * 8 + oo] = make_float2(s2[0], s2[1]);
    if (sl == 0) { es2[n] = tsv; ed2[n] = tdv; }
}

// ---------------- fused: w2 precompute + agg8 + log_softmax (1024 thr) ------

__global__ void __launch_bounds__(1024) agg8_lsm_kernel(
    const int* __restrict__ bcnt, const int* __restrict__ off,
    const int* __restrict__ deg, const ull* __restrict__ csre,
    const float* __restrict__ es2, const float* __restrict__ ed2,
    const float* __restrict__ h2, const float* __restrict__ b2,
    float* __restrict__ out, int N)
{
    __shared__ float w2v[CAP];
    __shared__ unsigned short svl[CAP];
    __shared__ float den2[256], ed2s[256];

    const int b = blockIdx.x, t = threadIdx.x;
    const int cnt = min(bcnt[b], CAP);
    const size_t base = (size_t)b * CAP;

    if (t < 256) {
        const int nodeT = t * 256 + b;
        den2[t] = 0.f;
        ed2s[t] = (nodeT < N) ? ed2[nodeT] : 0.f;
    }
    __syncthreads();

    for (int i = t; i < cnt; i += 1024) {
        const ull r = csre[base + i];
        const int sv   = (int)(r & 0xFFFFull);
        const int dloc = (int)((r >> 16) & 255);
        const float evv = __uint_as_float((unsigned)(r >> 32));
        float z = es2[sv] + ed2s[dloc];
        float l = z > 0.f ? z : 0.2f * z;
        float q = __expf(l);
        atomicAdd(&den2[dloc], q);
        w2v[i] = q * evv;
        svl[i] = (unsigned short)sv;
    }
    __syncthreads();

    const int wid = t >> 6, lane = t & 63;
    const int grp = lane >> 2, sl = lane & 3;
    const int nloc = wid * 16 + grp;
    const int n = nloc * 256 + b;
    if (n >= N) return;

    const int dg   = deg[n];
    const int lbeg = off[n] - (int)base;

    float a0 = 0.f, a1 = 0.f;

    for (int j0 = 0; j0 < dg; j0 += 4) {
        #pragma unroll
        for (int ts = 0; ts < 4; ++ts) {
            const int jj  = j0 + ts;
            const int idx = lbeg + min(jj, dg - 1);
            const int svt = (int)svl[idx];
            float wt = w2v[idx];
            wt = (jj < dg) ? wt : 0.f;
            const float2 f = *(const float2*)&h2[(size_t)svt * 8 + 2 * sl];
            a0 += wt * f.x;
            a1 += wt * f.y;
        }
    }

    const float inv = 1.f / (den2[nloc] + 1e-16f);
    float v0 = a0 * inv + b2[2 * sl];
    float v1 = a1 * inv + b2[2 * sl + 1];

    float vm = fmaxf(v0, v1);
    vm = fmaxf(vm, __shfl_xor(vm, 1));
    vm = fmaxf(vm, __shfl_xor(vm, 2));
    float s = __expf(v0 - vm) + __expf(v1 - vm);
    s += __shfl_xor(s, 1);
    s += __shfl_xor(s, 2);
    float lse = vm + logf(s);
    *(float2*)&out[(size_t)n * 8 + 2 * sl] = make_float2(v0 - lse, v1 - lse);
}

// ---------------------------------------------------------------------------

extern "C" void kernel_launch(void* const* d_in, const int* in_sizes, int n_in,
                              void* d_out, int out_size, void* d_ws, size_t ws_size,
                              hipStream_t stream)
{
    const float* x   = (const float*)d_in[0];
    const int*   ei  = (const int*)d_in[1];
    const float* ev  = (const float*)d_in[2];
    const float* W1  = (const float*)d_in[3];
    const float* a1s = (const float*)d_in[4];
    const float* a1d = (const float*)d_in[5];
    const float* b1  = (const float*)d_in[6];
    const float* W2  = (const float*)d_in[7];
    const float* a2s = (const float*)d_in[8];
    const float* a2d = (const float*)d_in[9];
    const float* b2  = (const float*)d_in[10];
    float* out = (float*)d_out;

    const int N = in_sizes[0] / 64;
    const int E = in_sizes[2];
    const int* srcp = ei;
    const int* dstp = ei + E;
    const int nchunks = (E + CHUNK - 1) / CHUNK;
    const int ngemm   = (N + 63) / 64;

    // Workspace: ped 256*CAP ull | csre 256*CAP ull | bcnt 256 |
    //            off N | deg N | es1 N | ed1 N | es2 N | ed2 N |
    //            h1 16N uint (fp8 x4) | h2 8N float
    ull*   ped  = (ull*)d_ws;
    ull*   csre = ped + (size_t)NBKT * CAP;
    int*   bcnt = (int*)(csre + (size_t)NBKT * CAP);
    int*   off  = bcnt + NBKT;
    int*   deg  = off + N;
    float* es1  = (float*)(deg + N);
    float* ed1  = es1 + N;
    float* es2  = ed1 + N;
    float* ed2  = es2 + N;
    unsigned* h1 = (unsigned*)(ed2 + N);            // 16N uints (64N fp8)
    float* h2   = (float*)(h1 + (size_t)N * 16);    // 8N floats

    hipMemsetAsync(bcnt, 0, NBKT * sizeof(int), stream);

    // [edge partition || layer-1 GEMM] in one launch
    part_gemm_kernel<<<nchunks + ngemm, 256, 0, stream>>>(
        srcp, dstp, ev, bcnt, ped, E, nchunks,
        x, W1, a1s, a1d, h1, es1, ed1, N);

    // CSR finalize + w1 precompute + layer-1 aggregation (256 blocks)
    csrw_agg64_kernel<<<NBKT, 1024, 0, stream>>>(
        ped, bcnt, es1, ed1, off, deg, csre,
        h1, b1, W2, a2s, a2d, h2, es2, ed2, N);

    // w2 precompute + layer-2 aggregation + log_softmax (256 blocks)
    agg8_lsm_kernel<<<NBKT, 1024, 0, stream>>>(
        bcnt, off, deg, csre, es2, ed2, h2, b2, out, N);
}

// Round 13
// 130.996 us; speedup vs baseline: 1.1276x; 1.0381x over previous
//
#include <hip/hip_runtime.h>
#include <hip/hip_fp16.h>
#include <math.h>

// ---------------------------------------------------------------------------
// RGAT (2-layer graph attention) on MI355X — round 29.
// N=50000, E=800000 (avg deg 16), IN=64, HID=64, OUT=8.
// Round-29: r28 (best, 136.0us) + instruction-count micro-opts. Evidence:
// overhead/latency-bound (all kernels < 45us, VALUBusy<14%, HBM<16%), so
// issue-count and barrier-count are the remaining controllable costs.
// (a) K1 partition loads vectorized: pass1 dst as int4, pass2 src/dst/ev as
//     int4/int4/float4 (4 edges/thread, 3 vec loads replace 12 scalar).
// (b) 16-barrier LDS scans (K1 partition, K2 CSR) -> wave __shfl_up scan +
//     4-entry cross-wave fixup: 2 barriers per scan instead of 16.
// All else identical to r28: 256 buckets (b=d&255, dloc=d>>8), CAP=4096,
// 1024-thr agg kernels, LDS-resident records, lean no-shfl hot loops,
// h1 fp8 e4m3 (3.2MB, L2-resident).
// ---------------------------------------------------------------------------

#define CHUNK 4096
#define NBKT  256
#define CAP   4096   // per-bucket capacity (mean 3125, >15-sigma margin)

typedef unsigned long long ull;
typedef float v2f __attribute__((ext_vector_type(2)));

struct PartSmem {
    int lhist[NBKT], lbase[NBKT], lcur[NBKT], gbase[NBKT], wsum[4];
    ull buf[CHUNK];
};
struct GemmSmem {
    float4 Wl[64 * 16];
    float  Xt[64 * 64];
};
union FusedSmem { PartSmem p; GemmSmem g; };

// ---------------- fused: edge partition (blocks < nchunks) + layer-1 GEMM ---

__global__ void __launch_bounds__(256) part_gemm_kernel(
    const int* __restrict__ src, const int* __restrict__ dst,
    const float* __restrict__ ev, int* __restrict__ bcnt,
    ull* __restrict__ ped, int E, int nchunks,
    const float* __restrict__ x, const float* __restrict__ W,
    const float* __restrict__ a_src, const float* __restrict__ a_dst,
    unsigned* __restrict__ h, float* __restrict__ es, float* __restrict__ ed,
    int N)
{
    __shared__ FusedSmem sm;
    const int t = threadIdx.x;

    if (blockIdx.x < nchunks) {
        // ---------------- partition path ----------------
        const int e0 = blockIdx.x * CHUNK;
        const int cnt = min(CHUNK, E - e0);
        const int cnt4 = cnt & ~3;
        sm.p.lhist[t] = 0;
        __syncthreads();

        // pass 1: histogram (int4-vectorized, 4 edges/thread)
        for (int i = t * 4; i < cnt4; i += 1024) {
            const int4 d4 = *(const int4*)&dst[e0 + i];
            atomicAdd(&sm.p.lhist[d4.x & 255], 1);
            atomicAdd(&sm.p.lhist[d4.y & 255], 1);
            atomicAdd(&sm.p.lhist[d4.z & 255], 1);
            atomicAdd(&sm.p.lhist[d4.w & 255], 1);
        }
        for (int i = cnt4 + t; i < cnt; i += 256)
            atomicAdd(&sm.p.lhist[dst[e0 + i] & 255], 1);
        __syncthreads();

        // scan via wave shuffles (2 barriers total)
        const int myc = sm.p.lhist[t];
        const int lane_ = t & 63, wv_ = t >> 6;
        int v = myc;
        #pragma unroll
        for (int o = 1; o < 64; o <<= 1) {
            int u = __shfl_up(v, o);
            if (lane_ >= o) v += u;
        }
        if (lane_ == 63) sm.p.wsum[wv_] = v;
        __syncthreads();
        int addw = 0;
        #pragma unroll
        for (int k = 0; k < 4; ++k) if (k < wv_) addw += sm.p.wsum[k];
        const int excl = v + addw - myc;
        sm.p.lbase[t] = excl;
        sm.p.lcur[t]  = excl;
        sm.p.gbase[t] = myc ? atomicAdd(&bcnt[t], myc) : 0;
        __syncthreads();

        // pass 2: pack into LDS, bucket-sorted (vectorized loads)
        for (int i = t * 4; i < cnt4; i += 1024) {
            const int4   s4 = *(const int4*)&src[e0 + i];
            const int4   d4 = *(const int4*)&dst[e0 + i];
            const float4 v4 = *(const float4*)&ev[e0 + i];
            {
                int b = d4.x & 255;
                unsigned p = (unsigned)s4.x | ((unsigned)(d4.x >> 8) << 16)
                           | ((unsigned)b << 24);
                ull q = (ull)p | ((ull)__float_as_uint(v4.x) << 32);
                sm.p.buf[atomicAdd(&sm.p.lcur[b], 1)] = q;
            }
            {
                int b = d4.y & 255;
                unsigned p = (unsigned)s4.y | ((unsigned)(d4.y >> 8) << 16)
                           | ((unsigned)b << 24);
                ull q = (ull)p | ((ull)__float_as_uint(v4.y) << 32);
                sm.p.buf[atomicAdd(&sm.p.lcur[b], 1)] = q;
            }
            {
                int b = d4.z & 255;
                unsigned p = (unsigned)s4.z | ((unsigned)(d4.z >> 8) << 16)
                           | ((unsigned)b << 24);
                ull q = (ull)p | ((ull)__float_as_uint(v4.z) << 32);
                sm.p.buf[atomicAdd(&sm.p.lcur[b], 1)] = q;
            }
            {
                int b = d4.w & 255;
                unsigned p = (unsigned)s4.w | ((unsigned)(d4.w >> 8) << 16)
                           | ((unsigned)b << 24);
                ull q = (ull)p | ((ull)__float_as_uint(v4.w) << 32);
                sm.p.buf[atomicAdd(&sm.p.lcur[b], 1)] = q;
            }
        }
        for (int i = cnt4 + t; i < cnt; i += 256) {
            int e = e0 + i;
            int d = dst[e];
            int b = d & 255;
            unsigned p = (unsigned)src[e] | ((unsigned)(d >> 8) << 16)
                       | ((unsigned)b << 24);
            ull q = (ull)p | ((ull)__float_as_uint(ev[e]) << 32);
            sm.p.buf[atomicAdd(&sm.p.lcur[b], 1)] = q;
        }
        __syncthreads();

        // pass 3: coalesced-by-bucket write to global
        for (int i = t; i < cnt; i += 256) {
            ull q = sm.p.buf[i];
            int b = (int)((q >> 24) & 255);
            ped[(size_t)b * CAP + sm.p.gbase[b] + i - sm.p.lbase[b]] = q;
        }
        return;
    }

    // ---------------- GEMM path ----------------
    const int n0 = (blockIdx.x - nchunks) * 64;

    #pragma unroll
    for (int i = 0; i < 4; ++i)
        sm.g.Wl[t + i * 256] = ((const float4*)W)[t + i * 256];

    #pragma unroll
    for (int i = 0; i < 4; ++i) {
        int f   = t + i * 256;
        int row = f >> 4, kq = f & 15;
        int grow = n0 + row;
        float4 v = make_float4(0.f, 0.f, 0.f, 0.f);
        if (grow < N) v = ((const float4*)x)[(size_t)grow * 16 + kq];
        int rs = row ^ ((kq & 3) << 2);
        sm.g.Xt[(kq * 4 + 0) * 64 + rs] = v.x;
        sm.g.Xt[(kq * 4 + 1) * 64 + rs] = v.y;
        sm.g.Xt[(kq * 4 + 2) * 64 + rs] = v.z;
        sm.g.Xt[(kq * 4 + 3) * 64 + rs] = v.w;
    }

    const int tx = t & 15;
    const int ty = t >> 4;
    const float4 asv = ((const float4*)a_src)[tx];
    const float4 adv = ((const float4*)a_dst)[tx];
    __syncthreads();

    float4 acc0 = make_float4(0.f,0.f,0.f,0.f);
    float4 acc1 = make_float4(0.f,0.f,0.f,0.f);
    float4 acc2 = make_float4(0.f,0.f,0.f,0.f);
    float4 acc3 = make_float4(0.f,0.f,0.f,0.f);

    #pragma unroll 8
    for (int k = 0; k < 64; ++k) {
        int swz = (k >> 2) & 3;
        const float4 xr = *(const float4*)&sm.g.Xt[k * 64 + ((ty ^ swz) << 2)];
        const float4 wv = sm.g.Wl[k * 16 + tx];
        acc0.x += xr.x * wv.x; acc0.y += xr.x * wv.y;
        acc0.z += xr.x * wv.z; acc0.w += xr.x * wv.w;
        acc1.x += xr.y * wv.x; acc1.y += xr.y * wv.y;
        acc1.z += xr.y * wv.z; acc1.w += xr.y * wv.w;
        acc2.x += xr.z * wv.x; acc2.y += xr.z * wv.y;
        acc2.z += xr.z * wv.z; acc2.w += xr.z * wv.w;
        acc3.x += xr.w * wv.x; acc3.y += xr.w * wv.y;
        acc3.z += xr.w * wv.z; acc3.w += xr.w * wv.w;
    }

    float4 accs[4] = {acc0, acc1, acc2, acc3};
    #pragma unroll
    for (int r = 0; r < 4; ++r) {
        int grow = n0 + ty * 4 + r;
        float4 a = accs[r];
        if (grow < N) {
            int lo = __builtin_amdgcn_cvt_pk_fp8_f32(a.x, a.y, 0, false);
            int pk = __builtin_amdgcn_cvt_pk_fp8_f32(a.z, a.w, lo, true);
            h[(size_t)grow * 16 + tx] = (unsigned)pk;
        }
        float ps = a.x * asv.x + a.y * asv.y + a.z * asv.z + a.w * asv.w;
        float pd = a.x * adv.x + a.y * adv.y + a.z * adv.z + a.w * adv.w;
        #pragma unroll
        for (int o = 8; o > 0; o >>= 1) {
            ps += __shfl_xor(ps, o);
            pd += __shfl_xor(pd, o);
        }
        if (tx == 0 && grow < N) { es[grow] = ps; ed[grow] = pd; }
    }
}

// ---------------- fused: CSR finalize + w1 precompute + agg64 (1024 thr) ----
// One block per bucket b (nodes n with n&255==b, slot dloc=n>>8, <=196
// nodes). Phase A: hist + shuffle-scan; scatter computes q1 once per edge;
// sv/w1 staged in LDS; den1 in LDS; csre written for K3. Phase B: 16 waves
// x 16 slots; hot loop: LDS record (free 4-lane broadcast) -> h1 gather.

__global__ void __launch_bounds__(1024) csrw_agg64_kernel(
    const ull* __restrict__ ped, const int* __restrict__ bcnt,
    const float* __restrict__ es1, const float* __restrict__ ed1,
    int* __restrict__ off, int* __restrict__ deg, ull* __restrict__ csre,
    const unsigned* __restrict__ h1, const float* __restrict__ b1,
    const float* __restrict__ W2, const float* __restrict__ a2s,
    const float* __restrict__ a2d, float* __restrict__ h2,
    float* __restrict__ es2, float* __restrict__ ed2, int N)
{
    __shared__ int    lhist[256], lbase[256], lcur[256], degl[256], wsum4[4];
    __shared__ float  den1[256], eds[256];
    __shared__ float  W2s[64 * 8];
    __shared__ float  w1v[CAP];
    __shared__ unsigned short svl[CAP];

    const int b = blockIdx.x, t = threadIdx.x;
    const int cnt = min(bcnt[b], CAP);
    const size_t base = (size_t)b * CAP;

    if (t < 256) {
        const int nodeT = t * 256 + b;      // slot t of bucket b
        lhist[t] = 0;
        den1[t] = 0.f;
        eds[t] = (nodeT < N) ? ed1[nodeT] : 0.f;
    }
    if (t < 128) ((float4*)W2s)[t] = ((const float4*)W2)[t];
    __syncthreads();

    for (int i = t; i < cnt; i += 1024)
        atomicAdd(&lhist[(int)((ped[base + i] >> 16) & 255)], 1);
    __syncthreads();

    // scan via wave shuffles (first 4 waves active)
    int myc = 0, v = 0;
    const int lane_ = t & 63, wv_ = t >> 6;
    if (t < 256) {
        myc = lhist[t];
        v = myc;
        #pragma unroll
        for (int o = 1; o < 64; o <<= 1) {
            int u = __shfl_up(v, o);
            if (lane_ >= o) v += u;
        }
        if (lane_ == 63) wsum4[wv_] = v;
    }
    __syncthreads();
    if (t < 256) {
        int addw = 0;
        #pragma unroll
        for (int k = 0; k < 4; ++k) if (k < wv_) addw += wsum4[k];
        const int excl = v + addw - myc;
        const int nodeT = t * 256 + b;
        lcur[t]  = excl;
        lbase[t] = excl;
        degl[t]  = myc;
        if (nodeT < N) { off[nodeT] = (int)base + excl; deg[nodeT] = myc; }
    }
    __syncthreads();

    // scatter + weight precompute (one exp per edge)
    for (int i = t; i < cnt; i += 1024) {
        const ull q = ped[base + i];
        const int sv   = (int)(q & 0xFFFFull);
        const int dloc = (int)((q >> 16) & 255);
        const float evv = __uint_as_float((unsigned)(q >> 32));
        float z = es1[sv] + eds[dloc];
        float l = z > 0.f ? z : 0.2f * z;
        float e = __expf(l);
        atomicAdd(&den1[dloc], e);
        const int pos = atomicAdd(&lcur[dloc], 1);
        w1v[pos] = e * evv;
        svl[pos] = (unsigned short)sv;
        csre[base + pos] = (q & 0xFFFFFFFF00000000ull)
                         | ((ull)(unsigned)(dloc << 16)) | (ull)(unsigned)sv;
    }
    __syncthreads();

    // ---------------- phase B: aggregation (16 waves x 16 slots) ---------
    const int wid = t >> 6, lane = t & 63;
    const int grp = lane >> 2, sl = lane & 3;
    const int nloc = wid * 16 + grp;
    const int n = nloc * 256 + b;
    if (n >= N) return;

    const int dg   = degl[nloc];
    const int lbeg = lbase[nloc];

    float acc[16];
    #pragma unroll
    for (int k = 0; k < 16; ++k) acc[k] = 0.f;

    for (int j0 = 0; j0 < dg; j0 += 4) {
        #pragma unroll
        for (int ts = 0; ts < 4; ++ts) {
            const int jj  = j0 + ts;
            const int idx = lbeg + min(jj, dg - 1);
            const int svt = (int)svl[idx];
            float wt = w1v[idx];
            wt = (jj < dg) ? wt : 0.f;
            const uint4 u = *(const uint4*)&h1[(size_t)svt * 16 + sl * 4];
            v2f fa = __builtin_amdgcn_cvt_pk_f32_fp8((int)u.x, false);
            v2f fb = __builtin_amdgcn_cvt_pk_f32_fp8((int)u.x, true);
            v2f fc = __builtin_amdgcn_cvt_pk_f32_fp8((int)u.y, false);
            v2f fd = __builtin_amdgcn_cvt_pk_f32_fp8((int)u.y, true);
            v2f fe = __builtin_amdgcn_cvt_pk_f32_fp8((int)u.z, false);
            v2f ff = __builtin_amdgcn_cvt_pk_f32_fp8((int)u.z, true);
            v2f fg = __builtin_amdgcn_cvt_pk_f32_fp8((int)u.w, false);
            v2f fh = __builtin_amdgcn_cvt_pk_f32_fp8((int)u.w, true);
            acc[0]  += wt * fa.x; acc[1]  += wt * fa.y;
            acc[2]  += wt * fb.x; acc[3]  += wt * fb.y;
            acc[4]  += wt * fc.x; acc[5]  += wt * fc.y;
            acc[6]  += wt * fd.x; acc[7]  += wt * fd.y;
            acc[8]  += wt * fe.x; acc[9]  += wt * fe.y;
            acc[10] += wt * ff.x; acc[11] += wt * ff.y;
            acc[12] += wt * fg.x; acc[13] += wt * fg.y;
            acc[14] += wt * fh.x; acc[15] += wt * fh.y;
        }
    }

    const float inv = 1.f / (den1[nloc] + 1e-16f);

    const float4 b1v0 = *(const float4*)&b1[sl * 16];
    const float4 b1v1 = *(const float4*)&b1[sl * 16 + 4];
    const float4 b1v2 = *(const float4*)&b1[sl * 16 + 8];
    const float4 b1v3 = *(const float4*)&b1[sl * 16 + 12];

    float hid[16];
    hid[0]  = fmaxf(acc[0]  * inv + b1v0.x, 0.f);
    hid[1]  = fmaxf(acc[1]  * inv + b1v0.y, 0.f);
    hid[2]  = fmaxf(acc[2]  * inv + b1v0.z, 0.f);
    hid[3]  = fmaxf(acc[3]  * inv + b1v0.w, 0.f);
    hid[4]  = fmaxf(acc[4]  * inv + b1v1.x, 0.f);
    hid[5]  = fmaxf(acc[5]  * inv + b1v1.y, 0.f);
    hid[6]  = fmaxf(acc[6]  * inv + b1v1.z, 0.f);
    hid[7]  = fmaxf(acc[7]  * inv + b1v1.w, 0.f);
    hid[8]  = fmaxf(acc[8]  * inv + b1v2.x, 0.f);
    hid[9]  = fmaxf(acc[9]  * inv + b1v2.y, 0.f);
    hid[10] = fmaxf(acc[10] * inv + b1v2.z, 0.f);
    hid[11] = fmaxf(acc[11] * inv + b1v2.w, 0.f);
    hid[12] = fmaxf(acc[12] * inv + b1v3.x, 0.f);
    hid[13] = fmaxf(acc[13] * inv + b1v3.y, 0.f);
    hid[14] = fmaxf(acc[14] * inv + b1v3.z, 0.f);
    hid[15] = fmaxf(acc[15] * inv + b1v3.w, 0.f);

    float p[8];
    #pragma unroll
    for (int o = 0; o < 8; ++o) p[o] = 0.f;
    #pragma unroll
    for (int k = 0; k < 16; ++k) {
        const float4 wA = *(const float4*)&W2s[(sl * 16 + k) * 8];
        const float4 wB = *(const float4*)&W2s[(sl * 16 + k) * 8 + 4];
        p[0] += hid[k] * wA.x; p[1] += hid[k] * wA.y;
        p[2] += hid[k] * wA.z; p[3] += hid[k] * wA.w;
        p[4] += hid[k] * wB.x; p[5] += hid[k] * wB.y;
        p[6] += hid[k] * wB.z; p[7] += hid[k] * wB.w;
    }
    float s4[4];
    {
        const bool hi = (sl & 1);
        #pragma unroll
        for (int k = 0; k < 4; ++k) {
            float keep = hi ? p[k + 4] : p[k];
            float send = hi ? p[k]     : p[k + 4];
            s4[k] = keep + __shfl_xor(send, 1);
        }
    }
    float s2[2];
    {
        const bool hi = (sl & 2);
        #pragma unroll
        for (int k = 0; k < 2; ++k) {
            float keep = hi ? s4[k + 2] : s4[k];
            float send = hi ? s4[k]     : s4[k + 2];
            s2[k] = keep + __shfl_xor(send, 2);
        }
    }
    const int oo = 4 * (sl & 1) + 2 * ((sl >> 1) & 1);

    float tsv = s2[0] * a2s[oo] + s2[1] * a2s[oo + 1];
    float tdv = s2[0] * a2d[oo] + s2[1] * a2d[oo + 1];
    tsv += __shfl_xor(tsv, 1); tdv += __shfl_xor(tdv, 1);
    tsv += __shfl_xor(tsv, 2); tdv += __shfl_xor(tdv, 2);

    *(float2*)&h2[(size_t)n * 8 + oo] = make_float2(s2[0], s2[1]);
    if (sl == 0) { es2[n] = tsv; ed2[n] = tdv; }
}

// ---------------- fused: w2 precompute + agg8 + log_softmax (1024 thr) ------

__global__ void __launch_bounds__(1024) agg8_lsm_kernel(
    const int* __restrict__ bcnt, const int* __restrict__ off,
    const int* __restrict__ deg, const ull* __restrict__ csre,
    const float* __restrict__ es2, const float* __restrict__ ed2,
    const float* __restrict__ h2, const float* __restrict__ b2,
    float* __restrict__ out, int N)
{
    __shared__ float w2v[CAP];
    __shared__ unsigned short svl[CAP];
    __shared__ float den2[256], ed2s[256];

    const int b = blockIdx.x, t = threadIdx.x;
    const int cnt = min(bcnt[b], CAP);
    const size_t base = (size_t)b * CAP;

    if (t < 256) {
        const int nodeT = t * 256 + b;
        den2[t] = 0.f;
        ed2s[t] = (nodeT < N) ? ed2[nodeT] : 0.f;
    }
    __syncthreads();

    for (int i = t; i < cnt; i += 1024) {
        const ull r = csre[base + i];
        const int sv   = (int)(r & 0xFFFFull);
        const int dloc = (int)((r >> 16) & 255);
        const float evv = __uint_as_float((unsigned)(r >> 32));
        float z = es2[sv] + ed2s[dloc];
        float l = z > 0.f ? z : 0.2f * z;
        float q = __expf(l);
        atomicAdd(&den2[dloc], q);
        w2v[i] = q * evv;
        svl[i] = (unsigned short)sv;
    }
    __syncthreads();

    const int wid = t >> 6, lane = t & 63;
    const int grp = lane >> 2, sl = lane & 3;
    const int nloc = wid * 16 + grp;
    const int n = nloc * 256 + b;
    if (n >= N) return;

    const int dg   = deg[n];
    const int lbeg = off[n] - (int)base;

    float a0 = 0.f, a1 = 0.f;

    for (int j0 = 0; j0 < dg; j0 += 4) {
        #pragma unroll
        for (int ts = 0; ts < 4; ++ts) {
            const int jj  = j0 + ts;
            const int idx = lbeg + min(jj, dg - 1);
            const int svt = (int)svl[idx];
            float wt = w2v[idx];
            wt = (jj < dg) ? wt : 0.f;
            const float2 f = *(const float2*)&h2[(size_t)svt * 8 + 2 * sl];
            a0 += wt * f.x;
            a1 += wt * f.y;
        }
    }

    const float inv = 1.f / (den2[nloc] + 1e-16f);
    float v0 = a0 * inv + b2[2 * sl];
    float v1 = a1 * inv + b2[2 * sl + 1];

    float vm = fmaxf(v0, v1);
    vm = fmaxf(vm, __shfl_xor(vm, 1));
    vm = fmaxf(vm, __shfl_xor(vm, 2));
    float s = __expf(v0 - vm) + __expf(v1 - vm);
    s += __shfl_xor(s, 1);
    s += __shfl_xor(s, 2);
    float lse = vm + logf(s);
    *(float2*)&out[(size_t)n * 8 + 2 * sl] = make_float2(v0 - lse, v1 - lse);
}

// ---------------------------------------------------------------------------

extern "C" void kernel_launch(void* const* d_in, const int* in_sizes, int n_in,
                              void* d_out, int out_size, void* d_ws, size_t ws_size,
                              hipStream_t stream)
{
    const float* x   = (const float*)d_in[0];
    const int*   ei  = (const int*)d_in[1];
    const float* ev  = (const float*)d_in[2];
    const float* W1  = (const float*)d_in[3];
    const float* a1s = (const float*)d_in[4];
    const float* a1d = (const float*)d_in[5];
    const float* b1  = (const float*)d_in[6];
    const float* W2  = (const float*)d_in[7];
    const float* a2s = (const float*)d_in[8];
    const float* a2d = (const float*)d_in[9];
    const float* b2  = (const float*)d_in[10];
    float* out = (float*)d_out;

    const int N = in_sizes[0] / 64;
    const int E = in_sizes[2];
    const int* srcp = ei;
    const int* dstp = ei + E;
    const int nchunks = (E + CHUNK - 1) / CHUNK;
    const int ngemm   = (N + 63) / 64;

    // Workspace: ped 256*CAP ull | csre 256*CAP ull | bcnt 256 |
    //            off N | deg N | es1 N | ed1 N | es2 N | ed2 N |
    //            h1 16N uint (fp8 x4) | h2 8N float
    ull*   ped  = (ull*)d_ws;
    ull*   csre = ped + (size_t)NBKT * CAP;
    int*   bcnt = (int*)(csre + (size_t)NBKT * CAP);
    int*   off  = bcnt + NBKT;
    int*   deg  = off + N;
    float* es1  = (float*)(deg + N);
    float* ed1  = es1 + N;
    float* es2  = ed1 + N;
    float* ed2  = es2 + N;
    unsigned* h1 = (unsigned*)(ed2 + N);            // 16N uints (64N fp8)
    float* h2   = (float*)(h1 + (size_t)N * 16);    // 8N floats

    hipMemsetAsync(bcnt, 0, NBKT * sizeof(int), stream);

    // [edge partition || layer-1 GEMM] in one launch
    part_gemm_kernel<<<nchunks + ngemm, 256, 0, stream>>>(
        srcp, dstp, ev, bcnt, ped, E, nchunks,
        x, W1, a1s, a1d, h1, es1, ed1, N);

    // CSR finalize + w1 precompute + layer-1 aggregation (256 blocks)
    csrw_agg64_kernel<<<NBKT, 1024, 0, stream>>>(
        ped, bcnt, es1, ed1, off, deg, csre,
        h1, b1, W2, a2s, a2d, h2, es2, ed2, N);

    // w2 precompute + layer-2 aggregation + log_softmax (256 blocks)
    agg8_lsm_kernel<<<NBKT, 1024, 0, stream>>>(
        bcnt, off, deg, csre, es2, ed2, h2, b2, out, N);
}